// Round 5
// baseline (178.904 us; speedup 1.0000x reference)
//
#include <hip/hip_runtime.h>
#include <hip/hip_bf16.h>

typedef __attribute__((ext_vector_type(8))) short bf16x8;
typedef __attribute__((ext_vector_type(4))) float f32x4;
typedef __attribute__((ext_vector_type(4))) unsigned short ushort4v;
typedef __attribute__((ext_vector_type(2))) unsigned uint2v;

__device__ __forceinline__ unsigned short f2bf(float f) {
  union { float f; unsigned u; } v; v.f = f;
  unsigned r = v.u + 0x7FFFu + ((v.u >> 16) & 1u);
  return (unsigned short)(r >> 16);
}

__device__ __forceinline__ unsigned pack_bf2(float lo, float hi) {
  __hip_bfloat162 h = __float22bfloat162_rn(make_float2(lo, hi));
  union { __hip_bfloat162 h; unsigned u; } cv; cv.h = h; return cv.u;
}

__device__ __forceinline__ void gll16(const void* g, void* l) {
  __builtin_amdgcn_global_load_lds((const __attribute__((address_space(1))) void*)g,
                                   (__attribute__((address_space(3))) void*)l, 16, 0, 0);
}

#define MFMA16(a, b, c) __builtin_amdgcn_mfma_f32_16x16x32_bf16((a), (b), (c), 0, 0, 0)

// ---------------------------------------------------------------- convert
__global__ void cvt_f32_bf16(const float* __restrict__ s, unsigned short* __restrict__ d, int n) {
  int i = (blockIdx.x * blockDim.x + threadIdx.x) * 4;
  if (i >= n) return;
  float4 f = *(const float4*)(s + i);
  ushort4v r;
  r[0] = f2bf(f.x); r[1] = f2bf(f.y); r[2] = f2bf(f.z); r[3] = f2bf(f.w);
  *(ushort4v*)(d + i) = r;
}

// ---------------------------------------------------------------- GEMM NT, 2-phase/K-tile, deep pipeline
// BM=256, BN=128, BK=64, 8 waves (4M x 2N). A: 2-deep dbuf; B: 3-deep ring.
// LDS element offsets: Ab(par)=par*16384 ; Bb(j)=32768+j*8192  (112 KiB total)
// Counted waits: stage A(t+2)+B(t+2) in phase 1; drain tile t+1 via vmcnt(6).
template<int EPI>
__global__ __launch_bounds__(512, 1)
void gemm8(const unsigned short* __restrict__ A,
           const unsigned short* __restrict__ B,
           unsigned short* __restrict__ obf,
           float* __restrict__ of32,
           int M, int N, int K) {
  extern __shared__ unsigned short lds[];
  const int tid = threadIdx.x, wid = tid >> 6, lane = tid & 63;
  const int c = lane & 15, g = lane >> 4;
  const int wr = wid >> 1, wc = wid & 1;
  const int nbn = N >> 7;
  const int nwg = gridDim.x;
  int wg = (blockIdx.x & 7) * (nwg >> 3) + (blockIdx.x >> 3);  // XCD swizzle (nwg%8==0)
  const int m0 = (wg / nbn) * 256, n0 = (wg % nbn) * 128;
  const int NT = K >> 6;
  const size_t rb = (size_t)K * 2;   // global row bytes
  const int swz = (c & 7) << 4;      // ds_read XOR key (16B granules)

  // pre-swizzled global source (m173): lane stages LDS (row8=l>>3, col16=l&7),
  // reads global col16 = (l&7)^row8
  const int r8 = lane >> 3;
  const char* Ag = (const char*)A + (size_t)m0 * rb + (size_t)r8 * rb + (size_t)(((lane & 7) ^ r8) * 16);
  const char* Bg = (const char*)B + (size_t)n0 * rb + (size_t)r8 * rb + (size_t)(((lane & 7) ^ r8) * 16);

  auto stageA = [&](int t, int par) {   // 32 chunks of 8 rows; wave does 4
#pragma unroll
    for (int j = 0; j < 4; ++j) {
      int ch = wid * 4 + j;
      gll16(Ag + (size_t)(ch * 8) * rb + t * 128, lds + par * 16384 + ch * 512);
    }
  };
  auto stageB = [&](int t, int bpar) {  // 16 chunks; wave does 2
#pragma unroll
    for (int j = 0; j < 2; ++j) {
      int ch = wid * 2 + j;
      gll16(Bg + (size_t)(ch * 8) * rb + t * 128, lds + 32768 + bpar * 8192 + ch * 512);
    }
  };

  f32x4 acc[4][4];
#pragma unroll
  for (int i = 0; i < 4; ++i)
#pragma unroll
    for (int j = 0; j < 4; ++j) acc[i][j] = f32x4{0.f, 0.f, 0.f, 0.f};

  // prologue: stage tiles 0 and 1; drain tile 0, keep tile 1's 6 loads in flight
  stageA(0, 0); stageB(0, 0); stageA(1, 1); stageB(1, 1);
  asm volatile("s_waitcnt vmcnt(6)" ::: "memory");
  __builtin_amdgcn_s_barrier();

  for (int t = 0; t < NT; ++t) {
    const int cur = t & 1;
    const int bcur = t % 3;
    const unsigned short* Ac = lds + cur * 16384;
    const unsigned short* Bc = lds + 32768 + bcur * 8192;
    // ---- phase 0: read A(all) + B(n0-1); MFMA (m0-3 x n0-1)
    bf16x8 af[4][2], bf0[2][2];
#pragma unroll
    for (int mi = 0; mi < 4; ++mi) {
      int arow = wr * 64 + mi * 16 + c;
#pragma unroll
      for (int kk = 0; kk < 2; ++kk)
        af[mi][kk] = *(const bf16x8*)((const char*)Ac + arow * 128 + ((kk * 64 + g * 16) ^ swz));
    }
#pragma unroll
    for (int ni = 0; ni < 2; ++ni) {
      int brow = wc * 64 + ni * 16 + c;
#pragma unroll
      for (int kk = 0; kk < 2; ++kk)
        bf0[ni][kk] = *(const bf16x8*)((const char*)Bc + brow * 128 + ((kk * 64 + g * 16) ^ swz));
    }
    __builtin_amdgcn_s_barrier();
    asm volatile("s_waitcnt lgkmcnt(0)" ::: "memory");
    __builtin_amdgcn_sched_barrier(0);
    __builtin_amdgcn_s_setprio(1);
#pragma unroll
    for (int kk = 0; kk < 2; ++kk)
#pragma unroll
      for (int mi = 0; mi < 4; ++mi)
#pragma unroll
        for (int ni = 0; ni < 2; ++ni)
          acc[mi][ni] = MFMA16(af[mi][kk], bf0[ni][kk], acc[mi][ni]);
    __builtin_amdgcn_s_setprio(0);
    __builtin_amdgcn_s_barrier();
    // ---- phase 1: read B(n2-3); stage A(t+2)+B(t+2); MFMA; counted drain of tile t+1
    bf16x8 bf1[2][2];
#pragma unroll
    for (int ni = 0; ni < 2; ++ni) {
      int brow = wc * 64 + (ni + 2) * 16 + c;
#pragma unroll
      for (int kk = 0; kk < 2; ++kk)
        bf1[ni][kk] = *(const bf16x8*)((const char*)Bc + brow * 128 + ((kk * 64 + g * 16) ^ swz));
    }
    const bool more = (t + 2 < NT);
    if (more) { stageA(t + 2, cur); stageB(t + 2, (t + 2) % 3); }
    __builtin_amdgcn_s_barrier();
    asm volatile("s_waitcnt lgkmcnt(0)" ::: "memory");
    __builtin_amdgcn_sched_barrier(0);
    __builtin_amdgcn_s_setprio(1);
#pragma unroll
    for (int kk = 0; kk < 2; ++kk)
#pragma unroll
      for (int mi = 0; mi < 4; ++mi)
#pragma unroll
        for (int ni = 0; ni < 2; ++ni)
          acc[mi][ni + 2] = MFMA16(af[mi][kk], bf1[ni][kk], acc[mi][ni + 2]);
    __builtin_amdgcn_s_setprio(0);
    if (more) { asm volatile("s_waitcnt vmcnt(6)" ::: "memory"); }
    else      { asm volatile("s_waitcnt vmcnt(0)" ::: "memory"); }
    __builtin_amdgcn_s_barrier();
  }

  // ---- epilogue
#pragma unroll
  for (int mi = 0; mi < 4; ++mi)
#pragma unroll
    for (int ni = 0; ni < 4; ++ni)
#pragma unroll
      for (int r4 = 0; r4 < 4; ++r4) {
        float v = acc[mi][ni][r4];
        int mg = m0 + wr * 64 + mi * 16 + g * 4 + r4;
        int ng = n0 + wc * 64 + ni * 16 + c;
        if (EPI == 0) {
          int which = ng >> 10, rem = ng & 1023;
          int hh = rem >> 6, dd = rem & 63;
          int bb = mg >> 11, tt = mg & 2047;
          size_t idx = (size_t)which * 8388608u + ((size_t)(bb * 16 + hh) * 2048 + tt) * 64 + dd;
          obf[idx] = f2bf(v);
        } else {
          of32[(size_t)mg * N + ng] = v;
        }
      }
}

// ---------------------------------------------------------------- flash attention (causal, swapped-QK^T)
__global__ __launch_bounds__(256, 6)
void attn_fwd(const unsigned short* __restrict__ qb,
              const unsigned short* __restrict__ kb,
              const unsigned short* __restrict__ vb,
              unsigned short* __restrict__ yb) {
  __shared__ unsigned short Kt[64 * 64];
  __shared__ unsigned short Vt[64 * 64];
  __shared__ unsigned short Pl[4 * 16 * 72];
  const int tid = threadIdx.x, w = tid >> 6, lane = tid & 63;
  const int c = lane & 15, g = lane >> 4;
  const int bh = blockIdx.x & 63;
  const int qt = 31 - (blockIdx.x >> 6);
  const int q0 = qt * 64;
  const int b = bh >> 4, h = bh & 15;
  const size_t hb = (size_t)bh * 131072;
  const float GAM = 0.125f * 1.44269504089f;

  const unsigned short* qp = qb + hb + (size_t)(q0 + w * 16 + c) * 64;
  bf16x8 qf0 = *(const bf16x8*)(qp + g * 8);
  bf16x8 qf1 = *(const bf16x8*)(qp + 32 + g * 8);

  f32x4 yacc[4];
#pragma unroll
  for (int i = 0; i < 4; ++i) yacc[i] = f32x4{0.f, 0.f, 0.f, 0.f};
  float mrun = -1e30f, lsum = 0.f;
  unsigned short* pw = Pl + w * (16 * 72);

  for (int kv = 0; kv <= qt; ++kv) {
    const int kv0 = kv * 64;
    const bool diag = (kv == qt);
    if (kv) __syncthreads();
#pragma unroll
    for (int r = 0; r < 2; ++r) {
      int chunk = w * 2 + r;
      int row = chunk * 8 + (lane >> 3);
      int bo = (lane & 7) * 16;
      int sbo = bo ^ ((row & 7) << 4);
      gll16((const char*)(kb + hb + (size_t)(kv0 + row) * 64) + sbo, Kt + chunk * 512);
    }
    {
      int kv2 = (lane & 31) * 2;
      int dblk = w * 16 + (lane >> 5) * 8;
      const unsigned short* vp = vb + hb + (size_t)(kv0 + kv2) * 64 + dblk;
      bf16x8 r0 = *(const bf16x8*)(vp);
      bf16x8 r1 = *(const bf16x8*)(vp + 64);
#pragma unroll
      for (int i = 0; i < 8; ++i) {
        int d = dblk + i;
        unsigned pk2 = ((unsigned)(unsigned short)r0[i]) | (((unsigned)(unsigned short)r1[i]) << 16);
        *(unsigned*)(Vt + d * 64 + (kv2 ^ ((d & 7) << 3))) = pk2;
      }
    }
    __syncthreads();

    f32x4 sacc[4];
#pragma unroll
    for (int nt = 0; nt < 4; ++nt) sacc[nt] = f32x4{0.f, 0.f, 0.f, 0.f};
#pragma unroll
    for (int kk = 0; kk < 2; ++kk)
#pragma unroll
      for (int nt = 0; nt < 4; ++nt) {
        int row = nt * 16 + c;
        bf16x8 kf = *(const bf16x8*)(Kt + row * 64 + ((kk * 32 + g * 8) ^ ((row & 7) << 3)));
        sacc[nt] = MFMA16(kf, (kk ? qf1 : qf0), sacc[nt]);
      }

    if (diag) {
      int ql = w * 16 + c;
#pragma unroll
      for (int nt = 0; nt < 4; ++nt)
#pragma unroll
        for (int r = 0; r < 4; ++r)
          if (nt * 16 + g * 4 + r > ql) sacc[nt][r] = -1e30f;
    }

    float m0 = -1e30f;
#pragma unroll
    for (int nt = 0; nt < 4; ++nt) {
      float a = fmaxf(fmaxf(sacc[nt][0], sacc[nt][1]), fmaxf(sacc[nt][2], sacc[nt][3]));
      m0 = fmaxf(m0, a);
    }
    m0 = fmaxf(m0, __shfl_xor(m0, 16));
    m0 = fmaxf(m0, __shfl_xor(m0, 32));

    if (__any(m0 > mrun + 32.0f)) {
      float mnew = fmaxf(mrun, m0);
      float corr = __builtin_amdgcn_exp2f(GAM * (mrun - mnew));
      lsum *= corr;
#pragma unroll
      for (int dt = 0; dt < 4; ++dt) yacc[dt] *= corr;
      mrun = mnew;
    }

    float bexp = -GAM * mrun;
    float psum = 0.f;
#pragma unroll
    for (int nt = 0; nt < 4; ++nt) {
      float p0 = __builtin_amdgcn_exp2f(fmaf(sacc[nt][0], GAM, bexp));
      float p1 = __builtin_amdgcn_exp2f(fmaf(sacc[nt][1], GAM, bexp));
      float p2 = __builtin_amdgcn_exp2f(fmaf(sacc[nt][2], GAM, bexp));
      float p3 = __builtin_amdgcn_exp2f(fmaf(sacc[nt][3], GAM, bexp));
      psum += (p0 + p1) + (p2 + p3);
      uint2v pkv;
      pkv[0] = pack_bf2(p0, p1);
      pkv[1] = pack_bf2(p2, p3);
      *(uint2v*)(pw + c * 72 + nt * 16 + g * 4) = pkv;
    }
    lsum += psum;

#pragma unroll
    for (int kk = 0; kk < 2; ++kk) {
      bf16x8 pb = *(const bf16x8*)(pw + c * 72 + kk * 32 + g * 8);
#pragma unroll
      for (int dt = 0; dt < 4; ++dt) {
        int n = dt * 16 + c;
        bf16x8 vf = *(const bf16x8*)(Vt + n * 64 + ((kk * 32 + g * 8) ^ ((n & 7) << 3)));
        yacc[dt] = MFMA16(vf, pb, yacc[dt]);
      }
    }
  }

  lsum += __shfl_xor(lsum, 16);
  lsum += __shfl_xor(lsum, 32);
  float inv = 1.0f / lsum;
  int row = q0 + w * 16 + c;
  unsigned short* yp = yb + ((size_t)(b * 2048 + row)) * 1024 + h * 64;
#pragma unroll
  for (int dt = 0; dt < 4; ++dt) {
    uint2v pkv;
    pkv[0] = pack_bf2(yacc[dt][0] * inv, yacc[dt][1] * inv);
    pkv[1] = pack_bf2(yacc[dt][2] * inv, yacc[dt][3] * inv);
    *(uint2v*)(yp + dt * 16 + g * 4) = pkv;
  }
}

// ---------------------------------------------------------------- launch
extern "C" void kernel_launch(void* const* d_in, const int* in_sizes, int n_in,
                              void* d_out, int out_size, void* d_ws, size_t ws_size,
                              hipStream_t stream) {
  const float* x     = (const float*)d_in[0];
  const float* wqkv  = (const float*)d_in[1];
  const float* wproj = (const float*)d_in[2];
  float* out = (float*)d_out;

  unsigned short* ws     = (unsigned short*)d_ws;
  unsigned short* xb     = ws;                       // 8388608
  unsigned short* wqkvb  = xb + 8388608;             // 3145728
  unsigned short* wprojb = wqkvb + 3145728;          // 1048576
  unsigned short* qkvb   = wprojb + 1048576;         // 3 * 8388608 (q,k,v)
  unsigned short* yb     = qkvb + 3 * 8388608;       // 8388608

  cvt_f32_bf16<<<8192, 256, 0, stream>>>(x, xb, 8388608);
  cvt_f32_bf16<<<3072, 256, 0, stream>>>(wqkv, wqkvb, 3145728);
  cvt_f32_bf16<<<1024, 256, 0, stream>>>(wproj, wprojb, 1048576);

  // LDS: A 2x256x64 + B 3x128x64 bf16 = 112 KiB
  gemm8<0><<<768, 512, 114688, stream>>>(xb, wqkvb, qkvb, nullptr, 8192, 3072, 1024);
  attn_fwd<<<2048, 256, 0, stream>>>(qkvb, qkvb + 8388608, qkvb + 2 * 8388608, yb);
  gemm8<1><<<256, 512, 114688, stream>>>(yb, wprojb, nullptr, out, 8192, 1024, 1024);
}